// Round 2
// 42998.953 us; speedup vs baseline: 4.0049x; 4.0049x over previous
//
#include <hip/hip_runtime.h>
#include <hip/hip_cooperative_groups.h>
#include <cmath>

namespace cg = cooperative_groups;

// JAX PRNG mode: 1 = threefry_partitionable (default in recent JAX).
#define JAX_PARTITIONABLE 1

#define NBLK 250
#define NTHR 512
#define DIM 1024
#define VOCAB 32000
#define TPROMPT 128
#define NEVENTS 256
#define TOPK 40
#define CAP 2048

// misc layout (ints, each counter on its own 64B line):
//  misc[0]              token value
//  misc[16]             tokens published count (release by sampler)
//  misc[32+16*j], j<4   layer-done counters (16 adds/step total)

// ---------------- Threefry-2x32 (exact JAX schedule) ----------------
__device__ __forceinline__ void tf2x32(unsigned k0, unsigned k1, unsigned x0, unsigned x1,
                                       unsigned& o0, unsigned& o1) {
  unsigned ks2 = k0 ^ k1 ^ 0x1BD11BDAu;
  x0 += k0; x1 += k1;
#define TFR(r) { x0 += x1; x1 = (x1 << (r)) | (x1 >> (32 - (r))); x1 ^= x0; }
  TFR(13) TFR(15) TFR(26) TFR(6)
  x0 += k1; x1 += ks2 + 1u;
  TFR(17) TFR(29) TFR(16) TFR(24)
  x0 += ks2; x1 += k0 + 2u;
  TFR(13) TFR(15) TFR(26) TFR(6)
  x0 += k0; x1 += k1 + 3u;
  TFR(17) TFR(29) TFR(16) TFR(24)
  x0 += k1; x1 += ks2 + 4u;
  TFR(13) TFR(15) TFR(26) TFR(6)
  x0 += ks2; x1 += k0 + 5u;
#undef TFR
  o0 = x0; o1 = x1;
}

__device__ __forceinline__ float gumbel_f(unsigned k0, unsigned k1, unsigned v) {
#pragma clang fp contract(off)
  unsigned bits;
#if JAX_PARTITIONABLE
  unsigned y0, y1; tf2x32(k0, k1, 0u, v, y0, y1);
  bits = y0 ^ y1;
#else
  unsigned y0, y1;
  if (v < 16000u) { tf2x32(k0, k1, v, v + 16000u, y0, y1); bits = y0; }
  else            { tf2x32(k0, k1, v - 16000u, v, y0, y1); bits = y1; }
#endif
  const float TINYF = 1.1754943508222875e-38f;
  float f  = __uint_as_float((bits >> 9) | 0x3f800000u);
  float fl = f - 1.0f;
  float u  = fmaxf(TINYF, fl + TINYF);
  float t1 = (float)log((double)u);
  float t3 = (float)log((double)(-t1));
  return -t3;
}

// XLA's exact f32 tanh (rational approx, no FMA)
__device__ __forceinline__ float xla_tanhf(float x) {
#pragma clang fp contract(off)
  const float kMax = 7.90531110763549805f;
  float xc = fminf(fmaxf(x, -kMax), kMax);
  float x2 = xc * xc;
  float num = xc * (4.89352455891786e-03f + x2 * (6.37261928875436e-04f +
              x2 * (1.48572235717979e-05f + x2 * (5.12229709037114e-08f +
              x2 * (-8.60467152213735e-11f + x2 * (2.00018790482477e-13f +
              x2 * (-2.76076847742355e-16f)))))));
  float den = 4.89352518554385e-03f + x2 * (2.26843463243900e-03f +
              x2 * (1.18534705686654e-04f + x2 * (1.19825839466702e-06f)));
  float r = num / den;
  return (fabsf(x) < 0.0004f) ? x : r;
}

__device__ __forceinline__ unsigned f2s(float x) {
  unsigned u = __float_as_uint(x);
  return (u & 0x80000000u) ? ~u : (u | 0x80000000u);
}
__device__ __forceinline__ float s2f(unsigned s) {
  unsigned u = (s & 0x80000000u) ? (s & 0x7fffffffu) : ~s;
  return __uint_as_float(u);
}

// ---------------- logits slice: v in [blk*128, blk*128+128) ----------------
__device__ void logits_slice(int blk, int tid, int s, const float* Wo, const float* ctx,
                             const float* temp_p, const float* pen_p, const int* counts,
                             const unsigned* k256, unsigned* skey, float* marr,
                             unsigned* ghist, float* hs, double* s_pd) {
  hs[tid] = ctx[tid];
  hs[tid + NTHR] = ctx[tid + NTHR];
  __syncthreads();
  const int vq = tid & 31, dg = tid >> 5;          // 32 float4-cols x 16 d-groups
  const int d0 = dg * 64;
  const float4* w4 = (const float4*)Wo + (size_t)d0 * (VOCAB / 4) + (blk * 32 + vq);
  double a0 = 0.0, a1 = 0.0, a2 = 0.0, a3 = 0.0;
#pragma unroll 8
  for (int j = 0; j < 64; ++j) {
    float4 w = w4[(size_t)j * (VOCAB / 4)];
    double h = (double)hs[d0 + j];
    a0 = fma(h, (double)w.x, a0);
    a1 = fma(h, (double)w.y, a1);
    a2 = fma(h, (double)w.z, a2);
    a3 = fma(h, (double)w.w, a3);
  }
  s_pd[dg * 128 + vq * 4 + 0] = a0;
  s_pd[dg * 128 + vq * 4 + 1] = a1;
  s_pd[dg * 128 + vq * 4 + 2] = a2;
  s_pd[dg * 128 + vq * 4 + 3] = a3;
  __syncthreads();
  if (tid < 128) {
#pragma clang fp contract(off)
    double acc = 0.0;
#pragma unroll
    for (int dgi = 0; dgi < 16; ++dgi) acc += s_pd[dgi * 128 + tid];
    int v = blk * 128 + tid;
    float lg = (float)acc;
    float l1 = lg / (*temp_p);
    if (counts[v] > 0) l1 = l1 / (*pen_p);
    unsigned key = f2s(l1);
    skey[v] = key;
    float g = gumbel_f(k256[2 * s], k256[2 * s + 1], (unsigned)v);
    marr[v] = l1 + g;
    atomicAdd(&ghist[key >> 21], 1u);
  }
  __syncthreads();
}

// ---------------- layer-15 slice: e in [lblk*64, lblk*64+64) ----------------
__device__ void layer_slice(int lblk, int tid, int i, const float* E, const float* Wl15,
                            float* ctx, int* misc, float* hs, double* s_rd, int* s_misc) {
  if (tid == 0) {
    while (__hip_atomic_load(misc + 16, __ATOMIC_ACQUIRE, __HIP_MEMORY_SCOPE_AGENT) < i + 1)
      __builtin_amdgcn_s_sleep(2);
    s_misc[7] = misc[0];
  }
  __syncthreads();
  const int tok = s_misc[7];
  const float* erow = E + (size_t)tok * DIM;
  hs[tid] = erow[tid];
  hs[tid + NTHR] = erow[tid + NTHR];
  __syncthreads();
  const int eL = tid & 63, dg = tid >> 6;          // 64 e-cols x 8 d-groups
  const int e = (lblk << 6) + eL;
  const float* w = Wl15 + (size_t)(dg * 128) * DIM + e;
  double acc = 0.0;
#pragma unroll 16
  for (int j = 0; j < 128; ++j)
    acc = fma((double)hs[dg * 128 + j], (double)w[(size_t)j * DIM], acc);
  s_rd[dg * 64 + eL] = acc;
  __syncthreads();
  if (tid < 64) {
    double a = 0.0;
#pragma unroll
    for (int dgi = 0; dgi < 8; ++dgi) a += s_rd[dgi * 64 + tid];
    float sv = (float)a + ctx[(lblk << 6) + tid];
    ctx[(lblk << 6) + tid] = xla_tanhf(sv);
  }
  __syncthreads();   // drain ctx stores (compiler emits vmcnt(0) before barrier)
  if (tid == 0)
    __hip_atomic_fetch_add(misc + 32 + 16 * (lblk & 3), 1,
                           __ATOMIC_RELEASE, __HIP_MEMORY_SCOPE_AGENT);
}

// ---------------- sampler (block 0); skey/marr/ghist ready via grid.sync ----------------
__device__ void sampler_phase(int i, const unsigned* skey, const float* marr,
                              int* counts, int* out, unsigned* ghist, int* misc,
                              unsigned* s_h, unsigned* s_sum, float* s_val, int* s_idx,
                              unsigned* s_ck, int* s_cv, float* s_cm, int* s_misc) {
  const int tid = threadIdx.x;
  if (tid == 1) s_misc[3] = 0;
  __syncthreads();

  // ---- pick the bucket (2048-bin hist built by logits blocks) ----
  const uint4* gh4 = (const uint4*)ghist;
  uint4 h4 = gh4[tid];
  s_sum[tid] = h4.x + h4.y + h4.z + h4.w;
  __syncthreads();
  for (int off = 1; off < NTHR; off <<= 1) {
    unsigned u = (tid + off < NTHR) ? s_sum[tid + off] : 0u;
    __syncthreads();
    s_sum[tid] += u;
    __syncthreads();
  }
  {
    unsigned above = (tid + 1 < NTHR) ? s_sum[tid + 1] : 0u;
    unsigned cum = above;
    unsigned hh[4] = { h4.x, h4.y, h4.z, h4.w };
#pragma unroll
    for (int bb = 3; bb >= 0; --bb) {
      unsigned c = hh[bb];
      if (cum < TOPK && cum + c >= TOPK) {
        s_misc[0] = 4 * tid + bb;
        s_misc[1] = (int)(TOPK - cum);
      }
      cum += c;
    }
  }
  __syncthreads();
  const int B = s_misc[0];
  int rr = s_misc[1];

  // ---- single fused sweep: candidates in bucket B + max over buckets > B ----
  float bm = -INFINITY; int bv = 0x7fffffff;
  const uint4* sk4 = (const uint4*)skey;
  const float4* mr4 = (const float4*)marr;
  for (int g = tid; g < VOCAB / 4; g += NTHR) {
    uint4 k4 = sk4[g];
    float4 m4 = mr4[g];
    unsigned kk[4] = { k4.x, k4.y, k4.z, k4.w };
    float mm[4] = { m4.x, m4.y, m4.z, m4.w };
#pragma unroll
    for (int c = 0; c < 4; ++c) {
      int b = (int)(kk[c] >> 21);
      int v = 4 * g + c;
      if (b > B) {
        if (mm[c] > bm || (mm[c] == bm && v < bv)) { bm = mm[c]; bv = v; }
      } else if (b == B) {
        int pos = atomicAdd(&s_misc[3], 1);
        if (pos < CAP) { s_ck[pos] = kk[c]; s_cv[pos] = v; s_cm[pos] = mm[c]; }
      }
    }
  }
  __syncthreads();
  const int cc = s_misc[3];
  unsigned pref = ((unsigned)B) << 21;
  const int sh_arr[3] = { 13, 5, 0 };
  const unsigned him_arr[3] = { 0xFFE00000u, 0xFFFFE000u, 0xFFFFFFE0u };
  const int nb_arr[3] = { 256, 256, 32 };
  const bool fits = (cc <= CAP);
  for (int p = 0; p < 3; ++p) {
    const int sh = sh_arr[p];
    const unsigned him = him_arr[p];
    const int nb = nb_arr[p];
    if (tid < nb) s_h[tid] = 0u;
    __syncthreads();
    if (fits) {
      for (int j = tid; j < cc; j += NTHR) {
        unsigned k = s_ck[j];
        if ((k & him) == pref) atomicAdd(&s_h[(k >> sh) & (unsigned)(nb - 1)], 1u);
      }
    } else {  // fallback: sweep global skey (not expected on this data)
      for (int v = tid; v < VOCAB; v += NTHR) {
        unsigned k = skey[v];
        if ((k & him) == pref) atomicAdd(&s_h[(k >> sh) & (unsigned)(nb - 1)], 1u);
      }
    }
    __syncthreads();
    for (int off = 1; off < nb; off <<= 1) {
      unsigned u = (tid < nb && tid + off < nb) ? s_h[tid + off] : 0u;
      __syncthreads();
      if (tid < nb) s_h[tid] += u;
      __syncthreads();
    }
    if (tid < nb) {
      unsigned ab = (tid + 1 < nb) ? s_h[tid + 1] : 0u;
      if ((int)ab < rr && rr <= (int)s_h[tid]) { s_misc[4] = tid; s_misc[5] = rr - (int)ab; }
    }
    __syncthreads();
    pref |= ((unsigned)s_misc[4]) << sh;
    rr = s_misc[5];
    __syncthreads();
  }
  const unsigned kth = pref;   // exact key of the 40th-largest penalized logit

  // ---- argmax of (l + gumbel) over kept set {key >= kth} ----
  if (fits) {
    for (int j = tid; j < cc; j += NTHR) {
      if (s_ck[j] >= kth) {
        float m = s_cm[j]; int v = s_cv[j];
        if (m > bm || (m == bm && v < bv)) { bm = m; bv = v; }
      }
    }
  } else {
    for (int v = tid; v < VOCAB; v += NTHR) {
      if (skey[v] >= kth) {
        float m = marr[v];
        if (m > bm || (m == bm && v < bv)) { bm = m; bv = v; }
      }
    }
  }
  // zero hist for next version (must precede token publish: consumers are
  // transitively ordered behind the release below)
  for (int g = tid; g < 2048; g += NTHR) ghist[g] = 0u;

  s_val[tid] = bm; s_idx[tid] = bv;
  __syncthreads();
  for (int s = NTHR / 2; s > 0; s >>= 1) {
    if (tid < s) {
      float ov = s_val[tid + s]; int oi = s_idx[tid + s];
      if (ov > s_val[tid] || (ov == s_val[tid] && oi < s_idx[tid])) {
        s_val[tid] = ov; s_idx[tid] = oi;
      }
    }
    __syncthreads();
  }
  if (tid == 0) {
    int tok = s_idx[0];
    counts[tok] += 1;                  // before release: logits read counts
    out[i] = tok;                      // harness reads d_out as int32
    misc[0] = tok;
    __hip_atomic_fetch_add(misc + 16, 1, __ATOMIC_RELEASE, __HIP_MEMORY_SCOPE_AGENT);
  }
  __syncthreads();
}

// ---------------- persistent cooperative kernel ----------------
__global__ void __launch_bounds__(NTHR, 2) tfxl_kernel(
    const int* __restrict__ ids, const float* __restrict__ E,
    const float* __restrict__ Wl, const float* __restrict__ Wo,
    const float* __restrict__ mems, const int* __restrict__ tcin,
    const float* __restrict__ temp_p, const float* __restrict__ pen_p,
    int* __restrict__ out,
    float* __restrict__ Ht, float* __restrict__ ctx,
    unsigned* __restrict__ skey, float* __restrict__ marr,
    int* __restrict__ counts, unsigned* __restrict__ k256,
    int* __restrict__ misc, unsigned* __restrict__ ghist) {
  cg::grid_group grid = cg::this_grid();
  const int tid = threadIdx.x;
  const int blk = blockIdx.x;

  __shared__ double smA[5120];         // 40KB: prompt tile | logits partials | sampler cands
  __shared__ float hs[DIM];            // 4KB
  __shared__ double s_rd[NTHR];        // 4KB
  __shared__ unsigned s_h[2048];       // 8KB
  __shared__ unsigned s_sum[NTHR];     // 2KB
  __shared__ float s_val[NTHR];        // 2KB
  __shared__ int s_idx[NTHR];          // 2KB
  __shared__ int s_misc[8];

  double* s_pd = smA;
  unsigned* s_ck = (unsigned*)smA;
  int* s_cv = (int*)(s_ck + CAP);
  float* s_cm = (float*)(s_cv + CAP);
  const float* Wl15 = Wl + (size_t)15 * DIM * DIM;

  // ---- P0: init Ht (transposed prompt embeddings), ctx15, counts, keys, flags ----
  {
    const int gsz = NBLK * NTHR;
    for (int g = blk * NTHR + tid; g < DIM * TPROMPT; g += gsz) {
      int t = g & 127, d = g >> 7;
      Ht[g] = E[(size_t)ids[t] * DIM + d];   // Ht[d*128+t]
    }
    int g = blk * NTHR + tid;
    if (g < DIM) ctx[g] = mems[((size_t)15 * 512 + 511) * DIM + g];  // mems[15, -1]
    if (g < VOCAB) counts[g] = tcin[g];
    if (g < NEVENTS) {
#if JAX_PARTITIONABLE
      unsigned y0, y1; tf2x32(0u, 42u, 0u, (unsigned)g, y0, y1);
      k256[2 * g] = y0; k256[2 * g + 1] = y1;
#else
      unsigned y0, y1, z0, z1;
      if (g < 128) {
        tf2x32(0u, 42u, (unsigned)(2 * g),     (unsigned)(2 * g + 256), y0, y1);
        tf2x32(0u, 42u, (unsigned)(2 * g + 1), (unsigned)(2 * g + 257), z0, z1);
        k256[2 * g] = y0; k256[2 * g + 1] = z0;
      } else {
        tf2x32(0u, 42u, (unsigned)(2 * g - 256), (unsigned)(2 * g),     y0, y1);
        tf2x32(0u, 42u, (unsigned)(2 * g - 255), (unsigned)(2 * g + 1), z0, z1);
        k256[2 * g] = y1; k256[2 * g + 1] = z1;
      }
#endif
    }
    if (g < 2048) ghist[g] = 0u;
    if (g < 256) misc[g] = 0;
  }
  grid.sync();

  // ---- prompt: ONLY layer 15 feeds the output token chain.
  //      16 blocks GEMM all 128 prompt tokens, then sequential tanh scan. ----
  if (blk < 16) {
    float* sc = (float*)smA;           // 64 x 129 tile
    int eL = tid & 63, tg = tid >> 6;
    int e = (blk << 6) + eL;
    const float* wl = Wl15 + e;
    const float* hbase = Ht + tg * 16;
    double acc[16];
#pragma unroll
    for (int k = 0; k < 16; ++k) acc[k] = 0.0;
    for (int d = 0; d < DIM; ++d) {
      float w = wl[(size_t)d * DIM];
      const float* hrow = hbase + d * 128;
#pragma unroll
      for (int k = 0; k < 16; ++k)
        acc[k] = fma((double)hrow[k], (double)w, acc[k]);
    }
#pragma unroll
    for (int k = 0; k < 16; ++k)
      sc[eL * 129 + tg * 16 + k] = (float)acc[k];
    __syncthreads();
    if (tid < 64) {
      float sv = ctx[(blk << 6) + tid];
      for (int t = 0; t < TPROMPT; ++t)
        sv = xla_tanhf(sc[tid * 129 + t] + sv);
      ctx[(blk << 6) + tid] = sv;
    }
    __syncthreads();
  }
  grid.sync();

  // ---- pred_logits (version 0); counts are initial tcin, no gating needed ----
  logits_slice(blk, tid, 0, Wo, ctx, temp_p, pen_p, counts, k256,
               skey, marr, ghist, hs, s_pd);
  grid.sync();

  // ---- generation loop: sampler -> (token flag) layer -> (layer flag) logits -> sync ----
  for (int i = 0; i < NEVENTS; ++i) {
    if (blk == 0)
      sampler_phase(i, skey, marr, counts, out, ghist, misc,
                    s_h, s_sum, s_val, s_idx, s_ck, s_cv, s_cm, s_misc);
    if (i == NEVENTS - 1) break;       // last model step is dead code
    if (blk >= 1 && blk <= 16)         // block 0 skips layer; starts during sampler tail
      layer_slice(blk - 1, tid, i, E, Wl15, ctx, misc, hs, s_rd, s_misc);
    if (tid == 0) {
      const int target = 16 * (i + 1);
      for (;;) {
        int sacc = 0;
#pragma unroll
        for (int j = 0; j < 4; ++j)
          sacc += __hip_atomic_load(misc + 32 + 16 * j, __ATOMIC_ACQUIRE,
                                    __HIP_MEMORY_SCOPE_AGENT);
        if (sacc >= target) break;
        __builtin_amdgcn_s_sleep(2);
      }
    }
    __syncthreads();
    logits_slice(blk, tid, i + 1, Wo, ctx, temp_p, pen_p, counts, k256,
                 skey, marr, ghist, hs, s_pd);
    grid.sync();                       // skey/marr/ghist complete before next sampler
  }
}

extern "C" void kernel_launch(void* const* d_in, const int* in_sizes, int n_in,
                              void* d_out, int out_size, void* d_ws, size_t ws_size,
                              hipStream_t stream) {
  const int*   ids  = (const int*)d_in[0];
  const float* E    = (const float*)d_in[1];
  const float* Wl   = (const float*)d_in[2];
  const float* Wo   = (const float*)d_in[3];
  const float* mems = (const float*)d_in[4];
  const int*   tcin = (const int*)d_in[5];
  const float* temp = (const float*)d_in[6];
  const float* pen  = (const float*)d_in[7];
  int* out = (int*)d_out;

  char* ws = (char*)d_ws;
  float*    Ht     = (float*)(ws + 0);        // 1024*128 f32 = 512KB
  float*    ctx    = (float*)(ws + 524288);   // 1024 f32 (layer-15 state)
  unsigned* skey   = (unsigned*)(ws + 589824);// 32000 u32
  float*    marr   = (float*)(ws + 720896);   // 32000 f32
  int*      counts = (int*)(ws + 851968);     // 32000 i32
  unsigned* k256   = (unsigned*)(ws + 979968);// 256*2 u32
  int*      misc   = (int*)(ws + 982016);     // 256 ints (flag lines)
  unsigned* ghist  = (unsigned*)(ws + 983040);// 2048 u32 key histogram
  // total < 1 MB

  void* args[] = { &ids, &E, &Wl, &Wo, &mems, &tcin, &temp, &pen, &out,
                   &Ht, &ctx, &skey, &marr, &counts, &k256, &misc, &ghist };
  hipLaunchCooperativeKernel((const void*)tfxl_kernel, dim3(NBLK), dim3(NTHR),
                             (void**)args, 0, stream);
}

// Round 3
// 35767.862 us; speedup vs baseline: 4.8145x; 1.2022x over previous
//
#include <hip/hip_runtime.h>
#include <hip/hip_cooperative_groups.h>
#include <cmath>

namespace cg = cooperative_groups;

// JAX PRNG mode: 1 = threefry_partitionable (default in recent JAX).
#define JAX_PARTITIONABLE 1

#define NBLK 250
#define NTHR 512
#define DIM 1024
#define VOCAB 32000
#define TPROMPT 128
#define NEVENTS 256
#define TOPK 40
#define CAP 2048

// misc layout (ints, each counter on its own 64B line):
//  misc[0]              token value
//  misc[16]             tokens published count (release by sampler)
//  misc[32+16*j], j<4   layer-done counters (16 adds/step total)

// ---------------- Threefry-2x32 (exact JAX schedule) ----------------
__device__ __forceinline__ void tf2x32(unsigned k0, unsigned k1, unsigned x0, unsigned x1,
                                       unsigned& o0, unsigned& o1) {
  unsigned ks2 = k0 ^ k1 ^ 0x1BD11BDAu;
  x0 += k0; x1 += k1;
#define TFR(r) { x0 += x1; x1 = (x1 << (r)) | (x1 >> (32 - (r))); x1 ^= x0; }
  TFR(13) TFR(15) TFR(26) TFR(6)
  x0 += k1; x1 += ks2 + 1u;
  TFR(17) TFR(29) TFR(16) TFR(24)
  x0 += ks2; x1 += k0 + 2u;
  TFR(13) TFR(15) TFR(26) TFR(6)
  x0 += k0; x1 += k1 + 3u;
  TFR(17) TFR(29) TFR(16) TFR(24)
  x0 += k1; x1 += ks2 + 4u;
  TFR(13) TFR(15) TFR(26) TFR(6)
  x0 += ks2; x1 += k0 + 5u;
#undef TFR
  o0 = x0; o1 = x1;
}

__device__ __forceinline__ float gumbel_f(unsigned k0, unsigned k1, unsigned v) {
#pragma clang fp contract(off)
  unsigned bits;
#if JAX_PARTITIONABLE
  unsigned y0, y1; tf2x32(k0, k1, 0u, v, y0, y1);
  bits = y0 ^ y1;
#else
  unsigned y0, y1;
  if (v < 16000u) { tf2x32(k0, k1, v, v + 16000u, y0, y1); bits = y0; }
  else            { tf2x32(k0, k1, v - 16000u, v, y0, y1); bits = y1; }
#endif
  const float TINYF = 1.1754943508222875e-38f;
  float f  = __uint_as_float((bits >> 9) | 0x3f800000u);
  float fl = f - 1.0f;
  float u  = fmaxf(TINYF, fl + TINYF);
  float t1 = (float)log((double)u);
  float t3 = (float)log((double)(-t1));
  return -t3;
}

// XLA's exact f32 tanh (rational approx, no FMA)
__device__ __forceinline__ float xla_tanhf(float x) {
#pragma clang fp contract(off)
  const float kMax = 7.90531110763549805f;
  float xc = fminf(fmaxf(x, -kMax), kMax);
  float x2 = xc * xc;
  float num = xc * (4.89352455891786e-03f + x2 * (6.37261928875436e-04f +
              x2 * (1.48572235717979e-05f + x2 * (5.12229709037114e-08f +
              x2 * (-8.60467152213735e-11f + x2 * (2.00018790482477e-13f +
              x2 * (-2.76076847742355e-16f)))))));
  float den = 4.89352518554385e-03f + x2 * (2.26843463243900e-03f +
              x2 * (1.18534705686654e-04f + x2 * (1.19825839466702e-06f)));
  float r = num / den;
  return (fabsf(x) < 0.0004f) ? x : r;
}

__device__ __forceinline__ unsigned f2s(float x) {
  unsigned u = __float_as_uint(x);
  return (u & 0x80000000u) ? ~u : (u | 0x80000000u);
}
__device__ __forceinline__ float s2f(unsigned s) {
  unsigned u = (s & 0x80000000u) ? (s & 0x7fffffffu) : ~s;
  return __uint_as_float(u);
}

// Single-wave (wave 0) suffix-scan bucket pick over s_h[0..nb):
// finds bin b such that (count of entries in bins > b) < rank <= (count >= b),
// writes dst[0] = b, dst[1] = rank - count_above.
__device__ __forceinline__ void pick_bin_wave(const unsigned* s_h, int nb, int rank,
                                              int* dst, int tid) {
  if (tid < 64) {
    const int l = tid;
    const int per = (nb + 63) >> 6;
    const int base = l * per;
    unsigned lsum = 0;
    for (int b = 0; b < per; ++b) {
      int idx = base + b;
      if (idx < nb) lsum += s_h[idx];
    }
    unsigned suf = lsum;                   // will become sum over lanes >= l
#pragma unroll
    for (int off = 1; off < 64; off <<= 1) {
      unsigned o = __shfl_down(suf, off);
      if (l + off < 64) suf += o;
    }
    unsigned above = suf - lsum;           // sum over lanes > l
    if ((int)above < rank && (int)suf >= rank) {
      unsigned cum = above;
      for (int b = per - 1; b >= 0; --b) {
        int idx = base + b;
        if (idx >= nb) continue;
        unsigned c = s_h[idx];
        if ((int)cum < rank && (int)(cum + c) >= rank) {
          dst[0] = idx;
          dst[1] = rank - (int)cum;
        }
        cum += c;
      }
    }
  }
}

// ---------------- logits slice: v in [blk*128, blk*128+128) ----------------
__device__ void logits_slice(int blk, int tid, int s, const float* Wo, const float* ctx,
                             const float* temp_p, const float* pen_p, const int* counts,
                             const unsigned* k256, unsigned* skey, float* marr,
                             unsigned* ghist, float* hs, double* s_pd, unsigned* s_h) {
  hs[tid] = ctx[tid];
  hs[tid + NTHR] = ctx[tid + NTHR];
  // zero per-block histogram (2048 bins)
  s_h[tid] = 0u; s_h[tid + 512] = 0u; s_h[tid + 1024] = 0u; s_h[tid + 1536] = 0u;
  __syncthreads();
  const int vq = tid & 31, dg = tid >> 5;          // 32 float4-cols x 16 d-groups
  const int d0 = dg * 64;
  const float4* w4 = (const float4*)Wo + (size_t)d0 * (VOCAB / 4) + (blk * 32 + vq);
  double a0 = 0.0, a1 = 0.0, a2 = 0.0, a3 = 0.0;
#pragma unroll 16
  for (int j = 0; j < 64; ++j) {
    float4 w = w4[(size_t)j * (VOCAB / 4)];
    double h = (double)hs[d0 + j];
    a0 = fma(h, (double)w.x, a0);
    a1 = fma(h, (double)w.y, a1);
    a2 = fma(h, (double)w.z, a2);
    a3 = fma(h, (double)w.w, a3);
  }
  s_pd[dg * 128 + vq * 4 + 0] = a0;
  s_pd[dg * 128 + vq * 4 + 1] = a1;
  s_pd[dg * 128 + vq * 4 + 2] = a2;
  s_pd[dg * 128 + vq * 4 + 3] = a3;
  __syncthreads();
  if (tid < 128) {
#pragma clang fp contract(off)
    double acc = 0.0;
#pragma unroll
    for (int dgi = 0; dgi < 16; ++dgi) acc += s_pd[dgi * 128 + tid];
    int v = blk * 128 + tid;
    float lg = (float)acc;
    float l1 = lg / (*temp_p);
    if (counts[v] > 0) l1 = l1 / (*pen_p);
    unsigned key = f2s(l1);
    skey[v] = key;
    float g = gumbel_f(k256[2 * s], k256[2 * s + 1], (unsigned)v);
    marr[v] = l1 + g;
    atomicAdd(&s_h[key >> 21], 1u);        // LDS pre-aggregation
  }
  __syncthreads();
  // flush occupied bins: at most one global atomic per bin per block
  {
    unsigned c;
    c = s_h[tid];        if (c) atomicAdd(&ghist[tid], c);
    c = s_h[tid + 512];  if (c) atomicAdd(&ghist[tid + 512], c);
    c = s_h[tid + 1024]; if (c) atomicAdd(&ghist[tid + 1024], c);
    c = s_h[tid + 1536]; if (c) atomicAdd(&ghist[tid + 1536], c);
  }
  __syncthreads();
}

// ---------------- layer-15 slice: e in [lblk*64, lblk*64+64) ----------------
__device__ void layer_slice(int lblk, int tid, int i, const float* E, const float* Wl15,
                            float* ctx, int* misc, float* hs, double* s_rd, int* s_misc) {
  if (tid == 0) {
    while (__hip_atomic_load(misc + 16, __ATOMIC_ACQUIRE, __HIP_MEMORY_SCOPE_AGENT) < i + 1)
      __builtin_amdgcn_s_sleep(2);
    s_misc[7] = misc[0];
  }
  __syncthreads();
  const int tok = s_misc[7];
  const float* erow = E + (size_t)tok * DIM;
  hs[tid] = erow[tid];
  hs[tid + NTHR] = erow[tid + NTHR];
  __syncthreads();
  const int eL = tid & 63, dg = tid >> 6;          // 64 e-cols x 8 d-groups
  const int e = (lblk << 6) + eL;
  const float* w = Wl15 + (size_t)(dg * 128) * DIM + e;
  double acc = 0.0;
#pragma unroll 16
  for (int j = 0; j < 128; ++j)
    acc = fma((double)hs[dg * 128 + j], (double)w[(size_t)j * DIM], acc);
  s_rd[dg * 64 + eL] = acc;
  __syncthreads();
  if (tid < 64) {
    double a = 0.0;
#pragma unroll
    for (int dgi = 0; dgi < 8; ++dgi) a += s_rd[dgi * 64 + tid];
    float sv = (float)a + ctx[(lblk << 6) + tid];
    ctx[(lblk << 6) + tid] = xla_tanhf(sv);
  }
  __syncthreads();   // drain ctx stores (compiler emits vmcnt(0) before barrier)
  if (tid == 0)
    __hip_atomic_fetch_add(misc + 32 + 16 * (lblk & 3), 1,
                           __ATOMIC_RELEASE, __HIP_MEMORY_SCOPE_AGENT);
}

// ---------------- sampler (block 0); skey/marr/ghist ready via grid.sync ----------------
__device__ void sampler_phase(int i, const unsigned* skey, const float* marr,
                              int* counts, int* out, unsigned* ghist, int* misc,
                              unsigned* s_h, float* s_val, int* s_idx,
                              unsigned* s_ck, int* s_cv, float* s_cm, int* s_misc) {
  const int tid = threadIdx.x;
  if (tid == 0) s_misc[3] = 0;
  // copy global hist to LDS (2048 bins)
  {
    const uint4* gh4 = (const uint4*)ghist;
    uint4 h4 = gh4[tid];
    s_h[4 * tid + 0] = h4.x; s_h[4 * tid + 1] = h4.y;
    s_h[4 * tid + 2] = h4.z; s_h[4 * tid + 3] = h4.w;
  }
  __syncthreads();

  // ---- pick the 11-bit bucket holding rank TOPK (single wave, no scan barriers) ----
  pick_bin_wave(s_h, 2048, TOPK, &s_misc[0], tid);
  __syncthreads();
  const int B = s_misc[0];
  int rr = s_misc[1];

  // ---- single fused sweep: candidates in bucket B + max over buckets > B ----
  float bm = -INFINITY; int bv = 0x7fffffff;
  const uint4* sk4 = (const uint4*)skey;
  const float4* mr4 = (const float4*)marr;
  for (int g = tid; g < VOCAB / 4; g += NTHR) {
    uint4 k4 = sk4[g];
    float4 m4 = mr4[g];
    unsigned kk[4] = { k4.x, k4.y, k4.z, k4.w };
    float mm[4] = { m4.x, m4.y, m4.z, m4.w };
#pragma unroll
    for (int c = 0; c < 4; ++c) {
      int b = (int)(kk[c] >> 21);
      int v = 4 * g + c;
      if (b > B) {
        if (mm[c] > bm || (mm[c] == bm && v < bv)) { bm = mm[c]; bv = v; }
      } else if (b == B) {
        int pos = atomicAdd(&s_misc[3], 1);
        if (pos < CAP) { s_ck[pos] = kk[c]; s_cv[pos] = v; s_cm[pos] = mm[c]; }
      }
    }
  }
  __syncthreads();
  const int cc = s_misc[3];
  unsigned pref = ((unsigned)B) << 21;
  const int sh_arr[3] = { 13, 5, 0 };
  const unsigned him_arr[3] = { 0xFFE00000u, 0xFFFFE000u, 0xFFFFFFE0u };
  const int nb_arr[3] = { 256, 256, 32 };
  const bool fits = (cc <= CAP);
  for (int p = 0; p < 3; ++p) {
    const int sh = sh_arr[p];
    const unsigned him = him_arr[p];
    const int nb = nb_arr[p];
    if (tid < nb) s_h[tid] = 0u;
    __syncthreads();
    if (fits) {
      for (int j = tid; j < cc; j += NTHR) {
        unsigned k = s_ck[j];
        if ((k & him) == pref) atomicAdd(&s_h[(k >> sh) & (unsigned)(nb - 1)], 1u);
      }
    } else {  // fallback: sweep global skey (not expected on this data)
      for (int v = tid; v < VOCAB; v += NTHR) {
        unsigned k = skey[v];
        if ((k & him) == pref) atomicAdd(&s_h[(k >> sh) & (unsigned)(nb - 1)], 1u);
      }
    }
    __syncthreads();
    pick_bin_wave(s_h, nb, rr, &s_misc[4], tid);
    __syncthreads();
    pref |= ((unsigned)s_misc[4]) << sh;
    rr = s_misc[5];
    __syncthreads();
  }
  const unsigned kth = pref;   // exact key of the 40th-largest penalized logit

  // ---- argmax of (l + gumbel) over kept set {key >= kth} ----
  if (fits) {
    for (int j = tid; j < cc; j += NTHR) {
      if (s_ck[j] >= kth) {
        float m = s_cm[j]; int v = s_cv[j];
        if (m > bm || (m == bm && v < bv)) { bm = m; bv = v; }
      }
    }
  } else {
    for (int v = tid; v < VOCAB; v += NTHR) {
      if (skey[v] >= kth) {
        float m = marr[v];
        if (m > bm || (m == bm && v < bv)) { bm = m; bv = v; }
      }
    }
  }
  // zero hist for next version (must precede token publish: consumers are
  // transitively ordered behind the release below)
  for (int g = tid; g < 2048; g += NTHR) ghist[g] = 0u;

  s_val[tid] = bm; s_idx[tid] = bv;
  __syncthreads();
  for (int s = NTHR / 2; s > 0; s >>= 1) {
    if (tid < s) {
      float ov = s_val[tid + s]; int oi = s_idx[tid + s];
      if (ov > s_val[tid] || (ov == s_val[tid] && oi < s_idx[tid])) {
        s_val[tid] = ov; s_idx[tid] = oi;
      }
    }
    __syncthreads();
  }
  if (tid == 0) {
    int tok = s_idx[0];
    counts[tok] += 1;                  // before release: logits read counts
    out[i] = tok;                      // harness reads d_out as int32
    misc[0] = tok;
    __hip_atomic_fetch_add(misc + 16, 1, __ATOMIC_RELEASE, __HIP_MEMORY_SCOPE_AGENT);
  }
  __syncthreads();
}

// ---------------- persistent cooperative kernel ----------------
__global__ void __launch_bounds__(NTHR, 2) tfxl_kernel(
    const int* __restrict__ ids, const float* __restrict__ E,
    const float* __restrict__ Wl, const float* __restrict__ Wo,
    const float* __restrict__ mems, const int* __restrict__ tcin,
    const float* __restrict__ temp_p, const float* __restrict__ pen_p,
    int* __restrict__ out,
    float* __restrict__ Ht, float* __restrict__ ctx,
    unsigned* __restrict__ skey, float* __restrict__ marr,
    int* __restrict__ counts, unsigned* __restrict__ k256,
    int* __restrict__ misc, unsigned* __restrict__ ghist) {
  cg::grid_group grid = cg::this_grid();
  const int tid = threadIdx.x;
  const int blk = blockIdx.x;

  __shared__ double smA[5120];         // 40KB: prompt tile | logits partials | sampler cands
  __shared__ float hs[DIM];            // 4KB
  __shared__ double s_rd[NTHR];        // 4KB
  __shared__ unsigned s_h[2048];       // 8KB: per-block hist | sampler hist/radix
  __shared__ float s_val[NTHR];        // 2KB
  __shared__ int s_idx[NTHR];          // 2KB
  __shared__ int s_misc[8];

  double* s_pd = smA;
  unsigned* s_ck = (unsigned*)smA;
  int* s_cv = (int*)(s_ck + CAP);
  float* s_cm = (float*)(s_cv + CAP);
  const float* Wl15 = Wl + (size_t)15 * DIM * DIM;

  // ---- P0: init Ht (transposed prompt embeddings), ctx15, counts, keys, flags ----
  {
    const int gsz = NBLK * NTHR;
    for (int g = blk * NTHR + tid; g < DIM * TPROMPT; g += gsz) {
      int t = g & 127, d = g >> 7;
      Ht[g] = E[(size_t)ids[t] * DIM + d];   // Ht[d*128+t]
    }
    int g = blk * NTHR + tid;
    if (g < DIM) ctx[g] = mems[((size_t)15 * 512 + 511) * DIM + g];  // mems[15, -1]
    if (g < VOCAB) counts[g] = tcin[g];
    if (g < NEVENTS) {
#if JAX_PARTITIONABLE
      unsigned y0, y1; tf2x32(0u, 42u, 0u, (unsigned)g, y0, y1);
      k256[2 * g] = y0; k256[2 * g + 1] = y1;
#else
      unsigned y0, y1, z0, z1;
      if (g < 128) {
        tf2x32(0u, 42u, (unsigned)(2 * g),     (unsigned)(2 * g + 256), y0, y1);
        tf2x32(0u, 42u, (unsigned)(2 * g + 1), (unsigned)(2 * g + 257), z0, z1);
        k256[2 * g] = y0; k256[2 * g + 1] = z0;
      } else {
        tf2x32(0u, 42u, (unsigned)(2 * g - 256), (unsigned)(2 * g),     y0, y1);
        tf2x32(0u, 42u, (unsigned)(2 * g - 255), (unsigned)(2 * g + 1), z0, z1);
        k256[2 * g] = y1; k256[2 * g + 1] = z1;
      }
#endif
    }
    if (g < 2048) ghist[g] = 0u;
    if (g < 256) misc[g] = 0;
  }
  grid.sync();

  // ---- prompt: ONLY layer 15 feeds the output token chain.
  //      16 blocks GEMM all 128 prompt tokens, then sequential tanh scan. ----
  if (blk < 16) {
    float* sc = (float*)smA;           // 64 x 129 tile
    int eL = tid & 63, tg = tid >> 6;
    int e = (blk << 6) + eL;
    const float* wl = Wl15 + e;
    const float* hbase = Ht + tg * 16;
    double acc[16];
#pragma unroll
    for (int k = 0; k < 16; ++k) acc[k] = 0.0;
    for (int d = 0; d < DIM; ++d) {
      float w = wl[(size_t)d * DIM];
      const float* hrow = hbase + d * 128;
#pragma unroll
      for (int k = 0; k < 16; ++k)
        acc[k] = fma((double)hrow[k], (double)w, acc[k]);
    }
#pragma unroll
    for (int k = 0; k < 16; ++k)
      sc[eL * 129 + tg * 16 + k] = (float)acc[k];
    __syncthreads();
    if (tid < 64) {
      float sv = ctx[(blk << 6) + tid];
      for (int t = 0; t < TPROMPT; ++t)
        sv = xla_tanhf(sc[tid * 129 + t] + sv);
      ctx[(blk << 6) + tid] = sv;
    }
    __syncthreads();
  }
  grid.sync();

  // ---- pred_logits (version 0); counts are initial tcin, no gating needed ----
  logits_slice(blk, tid, 0, Wo, ctx, temp_p, pen_p, counts, k256,
               skey, marr, ghist, hs, s_pd, s_h);
  grid.sync();

  // ---- generation loop: sampler -> (token flag) layer -> (layer flag) logits -> sync ----
  for (int i = 0; i < NEVENTS; ++i) {
    if (blk == 0)
      sampler_phase(i, skey, marr, counts, out, ghist, misc,
                    s_h, s_val, s_idx, s_ck, s_cv, s_cm, s_misc);
    if (i == NEVENTS - 1) break;       // last model step is dead code
    if (blk >= 1 && blk <= 16)         // block 0 skips layer; starts during sampler tail
      layer_slice(blk - 1, tid, i, E, Wl15, ctx, misc, hs, s_rd, s_misc);
    if (tid == 0) {
      const int target = 16 * (i + 1);
      for (;;) {
        int sacc = 0;
#pragma unroll
        for (int j = 0; j < 4; ++j)
          sacc += __hip_atomic_load(misc + 32 + 16 * j, __ATOMIC_ACQUIRE,
                                    __HIP_MEMORY_SCOPE_AGENT);
        if (sacc >= target) break;
        __builtin_amdgcn_s_sleep(2);
      }
    }
    __syncthreads();
    logits_slice(blk, tid, i + 1, Wo, ctx, temp_p, pen_p, counts, k256,
                 skey, marr, ghist, hs, s_pd, s_h);
    grid.sync();                       // skey/marr/ghist complete before next sampler
  }
}

extern "C" void kernel_launch(void* const* d_in, const int* in_sizes, int n_in,
                              void* d_out, int out_size, void* d_ws, size_t ws_size,
                              hipStream_t stream) {
  const int*   ids  = (const int*)d_in[0];
  const float* E    = (const float*)d_in[1];
  const float* Wl   = (const float*)d_in[2];
  const float* Wo   = (const float*)d_in[3];
  const float* mems = (const float*)d_in[4];
  const int*   tcin = (const int*)d_in[5];
  const float* temp = (const float*)d_in[6];
  const float* pen  = (const float*)d_in[7];
  int* out = (int*)d_out;

  char* ws = (char*)d_ws;
  float*    Ht     = (float*)(ws + 0);        // 1024*128 f32 = 512KB
  float*    ctx    = (float*)(ws + 524288);   // 1024 f32 (layer-15 state)
  unsigned* skey   = (unsigned*)(ws + 589824);// 32000 u32
  float*    marr   = (float*)(ws + 720896);   // 32000 f32
  int*      counts = (int*)(ws + 851968);     // 32000 i32
  unsigned* k256   = (unsigned*)(ws + 979968);// 256*2 u32
  int*      misc   = (int*)(ws + 982016);     // 256 ints (flag lines)
  unsigned* ghist  = (unsigned*)(ws + 983040);// 2048 u32 key histogram
  // total < 1 MB

  void* args[] = { &ids, &E, &Wl, &Wo, &mems, &tcin, &temp, &pen, &out,
                   &Ht, &ctx, &skey, &marr, &counts, &k256, &misc, &ghist };
  hipLaunchCooperativeKernel((const void*)tfxl_kernel, dim3(NBLK), dim3(NTHR),
                             (void**)args, 0, stream);
}

// Round 4
// 25406.966 us; speedup vs baseline: 6.7779x; 1.4078x over previous
//
#include <hip/hip_runtime.h>
#include <hip/hip_cooperative_groups.h>
#include <cmath>

namespace cg = cooperative_groups;

// JAX PRNG mode: 1 = threefry_partitionable (default in recent JAX).
#define JAX_PARTITIONABLE 1

#define NBLK 250
#define NTHR 1024
#define DIM 1024
#define VOCAB 32000
#define TPROMPT 128
#define NEVENTS 256
#define TOPK 40
#define CAP 2048

// misc layout (ints): misc[0] = token value, misc[16] = tokens published (release).

// ---------------- Threefry-2x32 (exact JAX schedule) ----------------
__device__ __forceinline__ void tf2x32(unsigned k0, unsigned k1, unsigned x0, unsigned x1,
                                       unsigned& o0, unsigned& o1) {
  unsigned ks2 = k0 ^ k1 ^ 0x1BD11BDAu;
  x0 += k0; x1 += k1;
#define TFR(r) { x0 += x1; x1 = (x1 << (r)) | (x1 >> (32 - (r))); x1 ^= x0; }
  TFR(13) TFR(15) TFR(26) TFR(6)
  x0 += k1; x1 += ks2 + 1u;
  TFR(17) TFR(29) TFR(16) TFR(24)
  x0 += ks2; x1 += k0 + 2u;
  TFR(13) TFR(15) TFR(26) TFR(6)
  x0 += k0; x1 += k1 + 3u;
  TFR(17) TFR(29) TFR(16) TFR(24)
  x0 += k1; x1 += ks2 + 4u;
  TFR(13) TFR(15) TFR(26) TFR(6)
  x0 += ks2; x1 += k0 + 5u;
#undef TFR
  o0 = x0; o1 = x1;
}

__device__ __forceinline__ float gumbel_f(unsigned k0, unsigned k1, unsigned v) {
#pragma clang fp contract(off)
  unsigned bits;
#if JAX_PARTITIONABLE
  unsigned y0, y1; tf2x32(k0, k1, 0u, v, y0, y1);
  bits = y0 ^ y1;
#else
  unsigned y0, y1;
  if (v < 16000u) { tf2x32(k0, k1, v, v + 16000u, y0, y1); bits = y0; }
  else            { tf2x32(k0, k1, v - 16000u, v, y0, y1); bits = y1; }
#endif
  const float TINYF = 1.1754943508222875e-38f;
  float f  = __uint_as_float((bits >> 9) | 0x3f800000u);
  float fl = f - 1.0f;
  float u  = fmaxf(TINYF, fl + TINYF);
  float t1 = (float)log((double)u);
  float t3 = (float)log((double)(-t1));
  return -t3;
}

// XLA's exact f32 tanh (rational approx, no FMA)
__device__ __forceinline__ float xla_tanhf(float x) {
#pragma clang fp contract(off)
  const float kMax = 7.90531110763549805f;
  float xc = fminf(fmaxf(x, -kMax), kMax);
  float x2 = xc * xc;
  float num = xc * (4.89352455891786e-03f + x2 * (6.37261928875436e-04f +
              x2 * (1.48572235717979e-05f + x2 * (5.12229709037114e-08f +
              x2 * (-8.60467152213735e-11f + x2 * (2.00018790482477e-13f +
              x2 * (-2.76076847742355e-16f)))))));
  float den = 4.89352518554385e-03f + x2 * (2.26843463243900e-03f +
              x2 * (1.18534705686654e-04f + x2 * (1.19825839466702e-06f)));
  float r = num / den;
  return (fabsf(x) < 0.0004f) ? x : r;
}

__device__ __forceinline__ unsigned f2s(float x) {
  unsigned u = __float_as_uint(x);
  return (u & 0x80000000u) ? ~u : (u | 0x80000000u);
}
__device__ __forceinline__ float s2f(unsigned s) {
  unsigned u = (s & 0x80000000u) ? (s & 0x7fffffffu) : ~s;
  return __uint_as_float(u);
}

// Single-wave (wave 0) suffix-scan bucket pick over s_h[0..nb):
// finds bin b with (count in bins > b) < rank <= (count >= b);
// dst[0] = b, dst[1] = rank - count_above.
__device__ __forceinline__ void pick_bin_wave(const unsigned* s_h, int nb, int rank,
                                              int* dst, int tid) {
  if (tid < 64) {
    const int l = tid;
    const int per = (nb + 63) >> 6;
    const int base = l * per;
    unsigned lsum = 0;
    for (int b = 0; b < per; ++b) {
      int idx = base + b;
      if (idx < nb) lsum += s_h[idx];
    }
    unsigned suf = lsum;                   // becomes sum over lanes >= l
#pragma unroll
    for (int off = 1; off < 64; off <<= 1) {
      unsigned o = __shfl_down(suf, off);
      if (l + off < 64) suf += o;
    }
    unsigned above = suf - lsum;           // sum over lanes > l
    if ((int)above < rank && (int)suf >= rank) {
      unsigned cum = above;
      for (int b = per - 1; b >= 0; --b) {
        int idx = base + b;
        if (idx >= nb) continue;
        unsigned c = s_h[idx];
        if ((int)cum < rank && (int)(cum + c) >= rank) {
          dst[0] = idx;
          dst[1] = rank - (int)cum;
        }
        cum += c;
      }
    }
  }
}

// ---------------- logits slice: v in [blk*128, blk*128+128) ----------------
__device__ void logits_slice(int blk, int tid, int s, const float* Wo, const float* ctx,
                             const float* temp_p, const float* pen_p, const int* counts,
                             const unsigned* k256, unsigned* skey, float* marr,
                             unsigned* ghist, float* hs, double* s_pd, unsigned* s_h) {
  hs[tid] = ctx[tid];
  // zero per-block histogram (2048 bins)
  s_h[tid] = 0u; s_h[tid + 1024] = 0u;
  __syncthreads();
  const int vq = tid & 31, dg = tid >> 5;          // 32 float4-cols x 32 d-groups
  const int d0 = dg * 32;
  const float4* w4 = (const float4*)Wo + (size_t)d0 * (VOCAB / 4) + (blk * 32 + vq);
  double a0 = 0.0, a1 = 0.0, a2 = 0.0, a3 = 0.0;
#pragma unroll 16
  for (int j = 0; j < 32; ++j) {
    float4 w = w4[(size_t)j * (VOCAB / 4)];
    double h = (double)hs[d0 + j];
    a0 = fma(h, (double)w.x, a0);
    a1 = fma(h, (double)w.y, a1);
    a2 = fma(h, (double)w.z, a2);
    a3 = fma(h, (double)w.w, a3);
  }
  s_pd[dg * 128 + vq * 4 + 0] = a0;
  s_pd[dg * 128 + vq * 4 + 1] = a1;
  s_pd[dg * 128 + vq * 4 + 2] = a2;
  s_pd[dg * 128 + vq * 4 + 3] = a3;
  __syncthreads();
  if (tid < 128) {
#pragma clang fp contract(off)
    double acc = 0.0;
#pragma unroll
    for (int dgi = 0; dgi < 32; ++dgi) acc += s_pd[dgi * 128 + tid];
    int v = blk * 128 + tid;
    float lg = (float)acc;
    float l1 = lg / (*temp_p);
    if (counts[v] > 0) l1 = l1 / (*pen_p);
    unsigned key = f2s(l1);
    skey[v] = key;
    float g = gumbel_f(k256[2 * s], k256[2 * s + 1], (unsigned)v);
    marr[v] = l1 + g;
    atomicAdd(&s_h[key >> 21], 1u);        // LDS pre-aggregation
  }
  __syncthreads();
  // flush occupied bins: at most one global atomic per bin per block
  {
    unsigned c;
    c = s_h[tid];        if (c) atomicAdd(&ghist[tid], c);
    c = s_h[tid + 1024]; if (c) atomicAdd(&ghist[tid + 1024], c);
  }
  __syncthreads();
}

// ---------------- layer-15 slice: e in [lblk*64, lblk*64+64) ----------------
__device__ void layer_slice(int lblk, int tid, int i, const float* E, const float* Wl15,
                            float* ctx, int* misc, float* hs, double* s_rd, int* s_misc) {
  if (tid == 0) {
    // relaxed poll (no per-iteration cache invalidate), bounded; then one acquire
    int spins = 0;
    while (__hip_atomic_load(misc + 16, __ATOMIC_RELAXED, __HIP_MEMORY_SCOPE_AGENT) < i + 1) {
      __builtin_amdgcn_s_sleep(2);
      if (++spins > (1 << 20)) break;
    }
    while (__hip_atomic_load(misc + 16, __ATOMIC_ACQUIRE, __HIP_MEMORY_SCOPE_AGENT) < i + 1)
      __builtin_amdgcn_s_sleep(8);         // normally 0 iterations
    s_misc[7] = misc[0];
  }
  __syncthreads();
  const int tok = s_misc[7];
  const float* erow = E + (size_t)tok * DIM;
  hs[tid] = erow[tid];
  __syncthreads();
  const int eL = tid & 63, dg = tid >> 6;          // 64 e-cols x 16 d-groups
  const int e = (lblk << 6) + eL;
  const float* w = Wl15 + (size_t)(dg * 64) * DIM + e;
  double acc = 0.0;
#pragma unroll 16
  for (int j = 0; j < 64; ++j)
    acc = fma((double)hs[dg * 64 + j], (double)w[(size_t)j * DIM], acc);
  s_rd[dg * 64 + eL] = acc;
  __syncthreads();
  if (tid < 64) {
    double a = 0.0;
#pragma unroll
    for (int dgi = 0; dgi < 16; ++dgi) a += s_rd[dgi * 64 + tid];
    float sv = (float)a + ctx[(lblk << 6) + tid];
    ctx[(lblk << 6) + tid] = xla_tanhf(sv);
  }
  __syncthreads();   // drain ctx stores; visibility carried by the grid.sync after
}

// ---------------- sampler (block 0); skey/marr/ghist ready via grid.sync ----------------
__device__ void sampler_phase(int i, const unsigned* skey, const float* marr,
                              int* counts, int* out, unsigned* ghist, int* misc,
                              unsigned* s_h, float* s_val, int* s_idx,
                              unsigned* s_ck, int* s_cv, float* s_cm, int* s_misc) {
  const int tid = threadIdx.x;
  if (tid == 0) s_misc[3] = 0;
  // copy global hist to LDS (2048 bins)
  if (tid < 512) {
    const uint4* gh4 = (const uint4*)ghist;
    uint4 h4 = gh4[tid];
    s_h[4 * tid + 0] = h4.x; s_h[4 * tid + 1] = h4.y;
    s_h[4 * tid + 2] = h4.z; s_h[4 * tid + 3] = h4.w;
  }
  __syncthreads();

  // ---- pick the 11-bit bucket holding rank TOPK ----
  pick_bin_wave(s_h, 2048, TOPK, &s_misc[0], tid);
  __syncthreads();
  const int B = s_misc[0];
  int rr = s_misc[1];

  // ---- single fused sweep: candidates in bucket B + max over buckets > B ----
  float bm = -INFINITY; int bv = 0x7fffffff;
  const uint4* sk4 = (const uint4*)skey;
  const float4* mr4 = (const float4*)marr;
  for (int g = tid; g < VOCAB / 4; g += NTHR) {
    uint4 k4 = sk4[g];
    float4 m4 = mr4[g];
    unsigned kk[4] = { k4.x, k4.y, k4.z, k4.w };
    float mm[4] = { m4.x, m4.y, m4.z, m4.w };
#pragma unroll
    for (int c = 0; c < 4; ++c) {
      int b = (int)(kk[c] >> 21);
      int v = 4 * g + c;
      if (b > B) {
        if (mm[c] > bm || (mm[c] == bm && v < bv)) { bm = mm[c]; bv = v; }
      } else if (b == B) {
        int pos = atomicAdd(&s_misc[3], 1);
        if (pos < CAP) { s_ck[pos] = kk[c]; s_cv[pos] = v; s_cm[pos] = mm[c]; }
      }
    }
  }
  __syncthreads();
  const int cc = s_misc[3];
  unsigned pref = ((unsigned)B) << 21;
  const int sh_arr[3] = { 13, 5, 0 };
  const unsigned him_arr[3] = { 0xFFE00000u, 0xFFFFE000u, 0xFFFFFFE0u };
  const int nb_arr[3] = { 256, 256, 32 };
  const bool fits = (cc <= CAP);
  for (int p = 0; p < 3; ++p) {
    const int sh = sh_arr[p];
    const unsigned him = him_arr[p];
    const int nb = nb_arr[p];
    if (tid < nb) s_h[tid] = 0u;
    __syncthreads();
    if (fits) {
      for (int j = tid; j < cc; j += NTHR) {
        unsigned k = s_ck[j];
        if ((k & him) == pref) atomicAdd(&s_h[(k >> sh) & (unsigned)(nb - 1)], 1u);
      }
    } else {  // fallback: sweep global skey (not expected on this data)
      for (int v = tid; v < VOCAB; v += NTHR) {
        unsigned k = skey[v];
        if ((k & him) == pref) atomicAdd(&s_h[(k >> sh) & (unsigned)(nb - 1)], 1u);
      }
    }
    __syncthreads();
    pick_bin_wave(s_h, nb, rr, &s_misc[4], tid);
    __syncthreads();
    pref |= ((unsigned)s_misc[4]) << sh;
    rr = s_misc[5];
    __syncthreads();
  }
  const unsigned kth = pref;   // exact key of the 40th-largest penalized logit

  // ---- argmax of (l + gumbel) over kept set {key >= kth} ----
  if (fits) {
    for (int j = tid; j < cc; j += NTHR) {
      if (s_ck[j] >= kth) {
        float m = s_cm[j]; int v = s_cv[j];
        if (m > bm || (m == bm && v < bv)) { bm = m; bv = v; }
      }
    }
  } else {
    for (int v = tid; v < VOCAB; v += NTHR) {
      if (skey[v] >= kth) {
        float m = marr[v];
        if (m > bm || (m == bm && v < bv)) { bm = m; bv = v; }
      }
    }
  }
  // zero hist for next version (ordered behind the release / block-0 grid.sync)
  for (int g = tid; g < 2048; g += NTHR) ghist[g] = 0u;

  s_val[tid] = bm; s_idx[tid] = bv;
  __syncthreads();
  for (int s = NTHR / 2; s > 0; s >>= 1) {
    if (tid < s) {
      float ov = s_val[tid + s]; int oi = s_idx[tid + s];
      if (ov > s_val[tid] || (ov == s_val[tid] && oi < s_idx[tid])) {
        s_val[tid] = ov; s_idx[tid] = oi;
      }
    }
    __syncthreads();
  }
  if (tid == 0) {
    int tok = s_idx[0];
    counts[tok] += 1;                  // before release: logits read counts
    out[i] = tok;                      // harness reads d_out as int32
    misc[0] = tok;
    __hip_atomic_fetch_add(misc + 16, 1, __ATOMIC_RELEASE, __HIP_MEMORY_SCOPE_AGENT);
  }
  __syncthreads();
}

// ---------------- persistent cooperative kernel ----------------
__global__ void __launch_bounds__(NTHR, 1) tfxl_kernel(
    const int* __restrict__ ids, const float* __restrict__ E,
    const float* __restrict__ Wl, const float* __restrict__ Wo,
    const float* __restrict__ mems, const int* __restrict__ tcin,
    const float* __restrict__ temp_p, const float* __restrict__ pen_p,
    int* __restrict__ out,
    float* __restrict__ Ht, float* __restrict__ ctx,
    unsigned* __restrict__ skey, float* __restrict__ marr,
    int* __restrict__ counts, unsigned* __restrict__ k256,
    int* __restrict__ misc, unsigned* __restrict__ ghist) {
  cg::grid_group grid = cg::this_grid();
  const int tid = threadIdx.x;
  const int blk = blockIdx.x;

  __shared__ double smA[5120];         // 40KB: prompt tile | logits partials | sampler cands
  __shared__ float hs[DIM];            // 4KB
  __shared__ double s_rd[NTHR];        // 8KB
  __shared__ unsigned s_h[2048];       // 8KB: per-block hist | sampler hist/radix
  __shared__ float s_val[NTHR];        // 4KB
  __shared__ int s_idx[NTHR];          // 4KB
  __shared__ int s_misc[8];

  double* s_pd = smA;
  unsigned* s_ck = (unsigned*)smA;
  int* s_cv = (int*)(s_ck + CAP);
  float* s_cm = (float*)(s_cv + CAP);
  const float* Wl15 = Wl + (size_t)15 * DIM * DIM;

  // ---- P0: init Ht (transposed prompt embeddings), ctx15, counts, keys, flags ----
  {
    const int gsz = NBLK * NTHR;
    for (int g = blk * NTHR + tid; g < DIM * TPROMPT; g += gsz) {
      int t = g & 127, d = g >> 7;
      Ht[g] = E[(size_t)ids[t] * DIM + d];   // Ht[d*128+t]
    }
    int g = blk * NTHR + tid;
    if (g < DIM) ctx[g] = mems[((size_t)15 * 512 + 511) * DIM + g];  // mems[15, -1]
    if (g < VOCAB) counts[g] = tcin[g];
    if (g < NEVENTS) {
#if JAX_PARTITIONABLE
      unsigned y0, y1; tf2x32(0u, 42u, 0u, (unsigned)g, y0, y1);
      k256[2 * g] = y0; k256[2 * g + 1] = y1;
#else
      unsigned y0, y1, z0, z1;
      if (g < 128) {
        tf2x32(0u, 42u, (unsigned)(2 * g),     (unsigned)(2 * g + 256), y0, y1);
        tf2x32(0u, 42u, (unsigned)(2 * g + 1), (unsigned)(2 * g + 257), z0, z1);
        k256[2 * g] = y0; k256[2 * g + 1] = z0;
      } else {
        tf2x32(0u, 42u, (unsigned)(2 * g - 256), (unsigned)(2 * g),     y0, y1);
        tf2x32(0u, 42u, (unsigned)(2 * g - 255), (unsigned)(2 * g + 1), z0, z1);
        k256[2 * g] = y1; k256[2 * g + 1] = z1;
      }
#endif
    }
    if (g < 2048) ghist[g] = 0u;
    if (g < 256) misc[g] = 0;
  }
  grid.sync();

  // ---- prompt: ONLY layer 15 feeds the output token chain.
  //      16 blocks GEMM all 128 prompt tokens, then sequential tanh scan. ----
  if (blk < 16) {
    float* sc = (float*)smA;           // 64 x 129 tile
    int eL = tid & 63, tg = tid >> 6;  // 16 t-groups x 8 tokens
    int e = (blk << 6) + eL;
    const float* wl = Wl15 + e;
    const float* hbase = Ht + tg * 8;
    double acc[8];
#pragma unroll
    for (int k = 0; k < 8; ++k) acc[k] = 0.0;
    for (int d = 0; d < DIM; ++d) {
      float w = wl[(size_t)d * DIM];
      const float* hrow = hbase + d * 128;
#pragma unroll
      for (int k = 0; k < 8; ++k)
        acc[k] = fma((double)hrow[k], (double)w, acc[k]);
    }
#pragma unroll
    for (int k = 0; k < 8; ++k)
      sc[eL * 129 + tg * 8 + k] = (float)acc[k];
    __syncthreads();
    if (tid < 64) {
      float sv = ctx[(blk << 6) + tid];
      for (int t = 0; t < TPROMPT; ++t)
        sv = xla_tanhf(sc[tid * 129 + t] + sv);
      ctx[(blk << 6) + tid] = sv;
    }
    __syncthreads();
  }
  grid.sync();

  // ---- pred_logits (version 0); counts are initial tcin ----
  logits_slice(blk, tid, 0, Wo, ctx, temp_p, pen_p, counts, k256,
               skey, marr, ghist, hs, s_pd, s_h);
  grid.sync();

  // ---- generation loop:
  //      sampler(blk0) -> token flag -> layer(blk1..16) -> grid.sync
  //      -> logits(all) -> grid.sync -> next sampler ----
  for (int i = 0; i < NEVENTS; ++i) {
    if (blk == 0)
      sampler_phase(i, skey, marr, counts, out, ghist, misc,
                    s_h, s_val, s_idx, s_ck, s_cv, s_cm, s_misc);
    if (i == NEVENTS - 1) break;       // last model step is dead code
    if (blk >= 1 && blk <= 16)
      layer_slice(blk - 1, tid, i, E, Wl15, ctx, misc, hs, s_rd, s_misc);
    grid.sync();                       // ctx + counts visible to all
    logits_slice(blk, tid, i + 1, Wo, ctx, temp_p, pen_p, counts, k256,
                 skey, marr, ghist, hs, s_pd, s_h);
    grid.sync();                       // skey/marr/ghist complete before next sampler
  }
}

extern "C" void kernel_launch(void* const* d_in, const int* in_sizes, int n_in,
                              void* d_out, int out_size, void* d_ws, size_t ws_size,
                              hipStream_t stream) {
  const int*   ids  = (const int*)d_in[0];
  const float* E    = (const float*)d_in[1];
  const float* Wl   = (const float*)d_in[2];
  const float* Wo   = (const float*)d_in[3];
  const float* mems = (const float*)d_in[4];
  const int*   tcin = (const int*)d_in[5];
  const float* temp = (const float*)d_in[6];
  const float* pen  = (const float*)d_in[7];
  int* out = (int*)d_out;

  char* ws = (char*)d_ws;
  float*    Ht     = (float*)(ws + 0);        // 1024*128 f32 = 512KB
  float*    ctx    = (float*)(ws + 524288);   // 1024 f32 (layer-15 state)
  unsigned* skey   = (unsigned*)(ws + 589824);// 32000 u32
  float*    marr   = (float*)(ws + 720896);   // 32000 f32
  int*      counts = (int*)(ws + 851968);     // 32000 i32
  unsigned* k256   = (unsigned*)(ws + 979968);// 256*2 u32
  int*      misc   = (int*)(ws + 982016);     // 256 ints (flag lines)
  unsigned* ghist  = (unsigned*)(ws + 983040);// 2048 u32 key histogram
  // total < 1 MB

  void* args[] = { &ids, &E, &Wl, &Wo, &mems, &tcin, &temp, &pen, &out,
                   &Ht, &ctx, &skey, &marr, &counts, &k256, &misc, &ghist };
  hipLaunchCooperativeKernel((const void*)tfxl_kernel, dim3(NBLK), dim3(NTHR),
                             (void**)args, 0, stream);
}

// Round 5
// 23457.085 us; speedup vs baseline: 7.3413x; 1.0831x over previous
//
#include <hip/hip_runtime.h>
#include <hip/hip_cooperative_groups.h>
#include <cmath>

namespace cg = cooperative_groups;

// JAX PRNG mode: 1 = threefry_partitionable (default in recent JAX).
#define JAX_PARTITIONABLE 1

#define NBLK 250
#define NTHR 1024
#define DIM 1024
#define VOCAB 32000
#define TPROMPT 128
#define NEVENTS 256
#define TOPK 40
#define CAP 2048
#define CAP_LIST 4096
#define RSPEC 160

// misc layout (ints, separate 64B lines):
//  misc[0]    token value
//  misc[16]   tokens published count (release by sampler)
//  misc[32+16*j], j<4  ctx-done counters (16 adds/step total)
//  misc[96]   speculative candidate list count (atomicAdd by logits blocks)
//  misc[112]  T_spec (uint bits) threshold for speculative append

// ---------------- Threefry-2x32 (exact JAX schedule) ----------------
__device__ __forceinline__ void tf2x32(unsigned k0, unsigned k1, unsigned x0, unsigned x1,
                                       unsigned& o0, unsigned& o1) {
  unsigned ks2 = k0 ^ k1 ^ 0x1BD11BDAu;
  x0 += k0; x1 += k1;
#define TFR(r) { x0 += x1; x1 = (x1 << (r)) | (x1 >> (32 - (r))); x1 ^= x0; }
  TFR(13) TFR(15) TFR(26) TFR(6)
  x0 += k1; x1 += ks2 + 1u;
  TFR(17) TFR(29) TFR(16) TFR(24)
  x0 += ks2; x1 += k0 + 2u;
  TFR(13) TFR(15) TFR(26) TFR(6)
  x0 += k0; x1 += k1 + 3u;
  TFR(17) TFR(29) TFR(16) TFR(24)
  x0 += k1; x1 += ks2 + 4u;
  TFR(13) TFR(15) TFR(26) TFR(6)
  x0 += ks2; x1 += k0 + 5u;
#undef TFR
  o0 = x0; o1 = x1;
}

__device__ __forceinline__ float gumbel_f(unsigned k0, unsigned k1, unsigned v) {
#pragma clang fp contract(off)
  unsigned bits;
#if JAX_PARTITIONABLE
  unsigned y0, y1; tf2x32(k0, k1, 0u, v, y0, y1);
  bits = y0 ^ y1;
#else
  unsigned y0, y1;
  if (v < 16000u) { tf2x32(k0, k1, v, v + 16000u, y0, y1); bits = y0; }
  else            { tf2x32(k0, k1, v - 16000u, v, y0, y1); bits = y1; }
#endif
  const float TINYF = 1.1754943508222875e-38f;
  float f  = __uint_as_float((bits >> 9) | 0x3f800000u);
  float fl = f - 1.0f;
  float u  = fmaxf(TINYF, fl + TINYF);
  float t1 = (float)log((double)u);
  float t3 = (float)log((double)(-t1));
  return -t3;
}

// XLA's exact f32 tanh (rational approx, no FMA)
__device__ __forceinline__ float xla_tanhf(float x) {
#pragma clang fp contract(off)
  const float kMax = 7.90531110763549805f;
  float xc = fminf(fmaxf(x, -kMax), kMax);
  float x2 = xc * xc;
  float num = xc * (4.89352455891786e-03f + x2 * (6.37261928875436e-04f +
              x2 * (1.48572235717979e-05f + x2 * (5.12229709037114e-08f +
              x2 * (-8.60467152213735e-11f + x2 * (2.00018790482477e-13f +
              x2 * (-2.76076847742355e-16f)))))));
  float den = 4.89352518554385e-03f + x2 * (2.26843463243900e-03f +
              x2 * (1.18534705686654e-04f + x2 * (1.19825839466702e-06f)));
  float r = num / den;
  return (fabsf(x) < 0.0004f) ? x : r;
}

__device__ __forceinline__ unsigned f2s(float x) {
  unsigned u = __float_as_uint(x);
  return (u & 0x80000000u) ? ~u : (u | 0x80000000u);
}
__device__ __forceinline__ float s2f(unsigned s) {
  unsigned u = (s & 0x80000000u) ? (s & 0x7fffffffu) : ~s;
  return __uint_as_float(u);
}

// Single-wave (wave 0) suffix-scan bucket pick over s_h[0..nb):
// finds bin b with (count in bins > b) < rank <= (count >= b);
// dst[0] = b, dst[1] = rank - count_above.
__device__ __forceinline__ void pick_bin_wave(const unsigned* s_h, int nb, int rank,
                                              int* dst, int tid) {
  if (tid < 64) {
    const int l = tid;
    const int per = (nb + 63) >> 6;
    const int base = l * per;
    unsigned lsum = 0;
    for (int b = 0; b < per; ++b) {
      int idx = base + b;
      if (idx < nb) lsum += s_h[idx];
    }
    unsigned suf = lsum;                   // becomes sum over lanes >= l
#pragma unroll
    for (int off = 1; off < 64; off <<= 1) {
      unsigned o = __shfl_down(suf, off);
      if (l + off < 64) suf += o;
    }
    unsigned above = suf - lsum;           // sum over lanes > l
    if ((int)above < rank && (int)suf >= rank) {
      unsigned cum = above;
      for (int b = per - 1; b >= 0; --b) {
        int idx = base + b;
        if (idx >= nb) continue;
        unsigned c = s_h[idx];
        if ((int)cum < rank && (int)(cum + c) >= rank) {
          dst[0] = idx;
          dst[1] = rank - (int)cum;
        }
        cum += c;
      }
    }
  }
}

// ---------------- logits slice: v in [blk*128, blk*128+128) ----------------
__device__ void logits_slice(int blk, int tid, int s, const float* Wo, const float* ctx,
                             const float* temp_p, const float* pen_p, const int* counts,
                             const unsigned* k256, unsigned* skey, float* marr,
                             unsigned* ghist, int* misc,
                             unsigned* gck, int* gcv, float* gcm,
                             float* hs, double* s_pd, unsigned* s_h) {
  hs[tid] = ctx[tid];
  // zero per-block histogram (2048 bins)
  s_h[tid] = 0u; s_h[tid + 1024] = 0u;
  __syncthreads();
  const int vq = tid & 31, dg = tid >> 5;          // 32 float4-cols x 32 d-groups
  const int d0 = dg * 32;
  const float4* w4 = (const float4*)Wo + (size_t)d0 * (VOCAB / 4) + (blk * 32 + vq);
  double a0 = 0.0, a1 = 0.0, a2 = 0.0, a3 = 0.0;
#pragma unroll 16
  for (int j = 0; j < 32; ++j) {
    float4 w = w4[(size_t)j * (VOCAB / 4)];
    double h = (double)hs[d0 + j];
    a0 = fma(h, (double)w.x, a0);
    a1 = fma(h, (double)w.y, a1);
    a2 = fma(h, (double)w.z, a2);
    a3 = fma(h, (double)w.w, a3);
  }
  s_pd[dg * 128 + vq * 4 + 0] = a0;
  s_pd[dg * 128 + vq * 4 + 1] = a1;
  s_pd[dg * 128 + vq * 4 + 2] = a2;
  s_pd[dg * 128 + vq * 4 + 3] = a3;
  __syncthreads();
  if (tid < 128) {
#pragma clang fp contract(off)
    double acc = 0.0;
#pragma unroll
    for (int dgi = 0; dgi < 32; ++dgi) acc += s_pd[dgi * 128 + tid];
    int v = blk * 128 + tid;
    float lg = (float)acc;
    float l1 = lg / (*temp_p);
    if (counts[v] > 0) l1 = l1 / (*pen_p);
    unsigned key = f2s(l1);
    skey[v] = key;
    float g = gumbel_f(k256[2 * s], k256[2 * s + 1], (unsigned)v);
    float m = l1 + g;
    marr[v] = m;
    atomicAdd(&s_h[key >> 21], 1u);        // LDS pre-aggregation
    // ---- speculative candidate append (key >= T_spec) ----
    unsigned tspec = (unsigned)misc[112];
    bool p = (key >= tspec);
    unsigned long long bal = __ballot(p);
    int lane = tid & 63;
    int base = 0;
    if (lane == 0) {
      int cnt = (int)__popcll(bal);
      if (cnt) base = atomicAdd(misc + 96, cnt);
    }
    base = __shfl(base, 0);
    if (p) {
      int pos = base + (int)__popcll(bal & ((1ULL << lane) - 1ULL));
      if (pos < CAP_LIST) { gck[pos] = key; gcv[pos] = v; gcm[pos] = m; }
    }
  }
  __syncthreads();
  // flush occupied bins: at most one global atomic per bin per block
  {
    unsigned c;
    c = s_h[tid];        if (c) atomicAdd(&ghist[tid], c);
    c = s_h[tid + 1024]; if (c) atomicAdd(&ghist[tid + 1024], c);
  }
  __syncthreads();
}

// ---------------- layer-15 slice: e in [lblk*64, lblk*64+64) ----------------
__device__ void layer_slice(int lblk, int tid, int i, const float* E, const float* Wl15,
                            float* ctx, int* misc, float* hs, double* s_rd, int* s_misc) {
  if (tid == 0) {
    // relaxed poll (no per-iteration cache invalidate), bounded; then one acquire
    int spins = 0;
    while (__hip_atomic_load(misc + 16, __ATOMIC_RELAXED, __HIP_MEMORY_SCOPE_AGENT) < i + 1) {
      __builtin_amdgcn_s_sleep(2);
      if (++spins > (1 << 22)) break;
    }
    while (__hip_atomic_load(misc + 16, __ATOMIC_ACQUIRE, __HIP_MEMORY_SCOPE_AGENT) < i + 1)
      __builtin_amdgcn_s_sleep(8);         // normally 0 iterations
    s_misc[7] = misc[0];
  }
  __syncthreads();
  const int tok = s_misc[7];
  const float* erow = E + (size_t)tok * DIM;
  hs[tid] = erow[tid];
  __syncthreads();
  const int eL = tid & 63, dg = tid >> 6;          // 64 e-cols x 16 d-groups
  const int e = (lblk << 6) + eL;
  const float* w = Wl15 + (size_t)(dg * 64) * DIM + e;
  double acc = 0.0;
#pragma unroll 16
  for (int j = 0; j < 64; ++j)
    acc = fma((double)hs[dg * 64 + j], (double)w[(size_t)j * DIM], acc);
  s_rd[dg * 64 + eL] = acc;
  __syncthreads();
  if (tid < 64) {
    double a = 0.0;
#pragma unroll
    for (int dgi = 0; dgi < 16; ++dgi) a += s_rd[dgi * 64 + tid];
    float sv = (float)a + ctx[(lblk << 6) + tid];
    ctx[(lblk << 6) + tid] = xla_tanhf(sv);
  }
  __syncthreads();   // drain ctx stores before the release below
  if (tid == 0)
    __hip_atomic_fetch_add(misc + 32 + 16 * (lblk & 3), 1,
                           __ATOMIC_RELEASE, __HIP_MEMORY_SCOPE_AGENT);
}

// ---------------- sampler (block 0); inputs ready via grid.sync ----------------
__device__ void sampler_phase(int i, const unsigned* skey, const float* marr,
                              int* counts, int* out, unsigned* ghist, int* misc,
                              const unsigned* gck, const int* gcv, const float* gcm,
                              unsigned* s_h, float* s_val, int* s_idx,
                              unsigned* s_ck, int* s_cv, float* s_cm, int* s_misc) {
  const int tid = threadIdx.x;
  if (tid == 0) s_misc[3] = 0;
  // copy global hist to LDS (2048 bins)
  if (tid < 512) {
    const uint4* gh4 = (const uint4*)ghist;
    uint4 h4 = gh4[tid];
    s_h[4 * tid + 0] = h4.x; s_h[4 * tid + 1] = h4.y;
    s_h[4 * tid + 2] = h4.z; s_h[4 * tid + 3] = h4.w;
  }
  __syncthreads();

  // ---- pick the 11-bit bucket holding rank TOPK, and the T_spec bucket (rank RSPEC) ----
  pick_bin_wave(s_h, 2048, TOPK, &s_misc[0], tid);
  pick_bin_wave(s_h, 2048, RSPEC, &s_misc[5], tid);   // writes s_misc[5], s_misc[6]
  __syncthreads();
  const int B = s_misc[0];
  int rr = s_misc[1];
  const int bt = s_misc[5];
  const int nc = misc[96];
  const unsigned tspec = (unsigned)misc[112];
  // fast path valid iff no list overflow and the list provably covers buckets >= B
  const bool fast = (nc <= CAP_LIST) && (tspec <= ((unsigned)B << 21));

  float bm = -INFINITY; int bv = 0x7fffffff;
  if (fast) {
    // candidates in bucket B + max over buckets > B, from the compact list
    for (int j = tid; j < nc; j += NTHR) {
      unsigned k = gck[j];
      int b = (int)(k >> 21);
      if (b > B) {
        float m = gcm[j]; int v = gcv[j];
        if (m > bm || (m == bm && v < bv)) { bm = m; bv = v; }
      } else if (b == B) {
        int pos = atomicAdd(&s_misc[3], 1);
        if (pos < CAP) { s_ck[pos] = k; s_cv[pos] = gcv[j]; s_cm[pos] = gcm[j]; }
      }
    }
  } else {
    // full fallback sweep over skey/marr (step 0, or spec-threshold drift)
    const uint4* sk4 = (const uint4*)skey;
    const float4* mr4 = (const float4*)marr;
    for (int g = tid; g < VOCAB / 4; g += NTHR) {
      uint4 k4 = sk4[g];
      float4 m4 = mr4[g];
      unsigned kk[4] = { k4.x, k4.y, k4.z, k4.w };
      float mm[4] = { m4.x, m4.y, m4.z, m4.w };
#pragma unroll
      for (int c = 0; c < 4; ++c) {
        int b = (int)(kk[c] >> 21);
        int v = 4 * g + c;
        if (b > B) {
          if (mm[c] > bm || (mm[c] == bm && v < bv)) { bm = mm[c]; bv = v; }
        } else if (b == B) {
          int pos = atomicAdd(&s_misc[3], 1);
          if (pos < CAP) { s_ck[pos] = kk[c]; s_cv[pos] = v; s_cm[pos] = mm[c]; }
        }
      }
    }
  }
  __syncthreads();
  const int cc = s_misc[3];
  unsigned pref = ((unsigned)B) << 21;
  const int sh_arr[3] = { 13, 5, 0 };
  const unsigned him_arr[3] = { 0xFFE00000u, 0xFFFFE000u, 0xFFFFFFE0u };
  const int nb_arr[3] = { 256, 256, 32 };
  const bool fits = (cc <= CAP);
  for (int p = 0; p < 3; ++p) {
    const int sh = sh_arr[p];
    const unsigned him = him_arr[p];
    const int nb = nb_arr[p];
    if (tid < nb) s_h[tid] = 0u;
    __syncthreads();
    if (fits) {
      for (int j = tid; j < cc; j += NTHR) {
        unsigned k = s_ck[j];
        if ((k & him) == pref) atomicAdd(&s_h[(k >> sh) & (unsigned)(nb - 1)], 1u);
      }
    } else {  // pathological bucket size: refine against global skey
      for (int v = tid; v < VOCAB; v += NTHR) {
        unsigned k = skey[v];
        if ((k & him) == pref) atomicAdd(&s_h[(k >> sh) & (unsigned)(nb - 1)], 1u);
      }
    }
    __syncthreads();
    pick_bin_wave(s_h, nb, rr, &s_misc[4], tid);
    __syncthreads();
    pref |= ((unsigned)s_misc[4]) << sh;
    rr = s_misc[5];
    __syncthreads();
  }
  const unsigned kth = pref;   // exact key of the 40th-largest penalized logit

  // ---- argmax of (l + gumbel) over kept set {key >= kth} ----
  if (fits) {
    for (int j = tid; j < cc; j += NTHR) {
      if (s_ck[j] >= kth) {
        float m = s_cm[j]; int v = s_cv[j];
        if (m > bm || (m == bm && v < bv)) { bm = m; bv = v; }
      }
    }
  } else {
    for (int v = tid; v < VOCAB; v += NTHR) {
      if (skey[v] >= kth) {
        float m = marr[v];
        if (m > bm || (m == bm && v < bv)) { bm = m; bv = v; }
      }
    }
  }
  // ---- next-step T_spec + resets (ordered before the token-publish release) ----
  if (tid == 0) {
    misc[112] = (int)(((unsigned)bt) << 21);   // lower bound of rank-RSPEC bucket
    misc[96] = 0;                              // candidate list count
  }
  for (int g = tid; g < 2048; g += NTHR) ghist[g] = 0u;

  s_val[tid] = bm; s_idx[tid] = bv;
  __syncthreads();
  for (int s = NTHR / 2; s > 0; s >>= 1) {
    if (tid < s) {
      float ov = s_val[tid + s]; int oi = s_idx[tid + s];
      if (ov > s_val[tid] || (ov == s_val[tid] && oi < s_idx[tid])) {
        s_val[tid] = ov; s_idx[tid] = oi;
      }
    }
    __syncthreads();
  }
  if (tid == 0) {
    int tok = s_idx[0];
    counts[tok] += 1;                  // before release: logits read counts
    out[i] = tok;                      // harness reads d_out as int32
    misc[0] = tok;
    __hip_atomic_fetch_add(misc + 16, 1, __ATOMIC_RELEASE, __HIP_MEMORY_SCOPE_AGENT);
  }
  __syncthreads();
}

// ---------------- persistent cooperative kernel ----------------
__global__ void __launch_bounds__(NTHR, 1) tfxl_kernel(
    const int* __restrict__ ids, const float* __restrict__ E,
    const float* __restrict__ Wl, const float* __restrict__ Wo,
    const float* __restrict__ mems, const int* __restrict__ tcin,
    const float* __restrict__ temp_p, const float* __restrict__ pen_p,
    int* __restrict__ out,
    float* __restrict__ Ht, float* __restrict__ ctx,
    unsigned* __restrict__ skey, float* __restrict__ marr,
    int* __restrict__ counts, unsigned* __restrict__ k256,
    int* __restrict__ misc, unsigned* __restrict__ ghist) {
  cg::grid_group grid = cg::this_grid();
  const int tid = threadIdx.x;
  const int blk = blockIdx.x;

  __shared__ double smA[5120];         // 40KB: prompt tile | logits partials | sampler cands
  __shared__ float hs[DIM];            // 4KB
  __shared__ double s_rd[NTHR];        // 8KB
  __shared__ unsigned s_h[2048];       // 8KB: per-block hist | sampler hist/radix
  __shared__ float s_val[NTHR];        // 4KB
  __shared__ int s_idx[NTHR];          // 4KB
  __shared__ int s_misc[8];

  double* s_pd = smA;
  unsigned* s_ck = (unsigned*)smA;
  int* s_cv = (int*)(s_ck + CAP);
  float* s_cm = (float*)(s_cv + CAP);
  const float* Wl15 = Wl + (size_t)15 * DIM * DIM;
  // speculative candidate list lives in the (post-prompt dead) Ht buffer
  unsigned* gck = (unsigned*)Ht;               // 4096 u32
  int*      gcv = (int*)(Ht + CAP_LIST);       // 4096 i32
  float*    gcm = (float*)(Ht + 2 * CAP_LIST); // 4096 f32

  // ---- P0: init Ht (transposed prompt embeddings), ctx15, counts, keys, flags ----
  {
    const int gsz = NBLK * NTHR;
    for (int g = blk * NTHR + tid; g < DIM * TPROMPT; g += gsz) {
      int t = g & 127, d = g >> 7;
      Ht[g] = E[(size_t)ids[t] * DIM + d];   // Ht[d*128+t]
    }
    int g = blk * NTHR + tid;
    if (g < DIM) ctx[g] = mems[((size_t)15 * 512 + 511) * DIM + g];  // mems[15, -1]
    if (g < VOCAB) counts[g] = tcin[g];
    if (g < NEVENTS) {
#if JAX_PARTITIONABLE
      unsigned y0, y1; tf2x32(0u, 42u, 0u, (unsigned)g, y0, y1);
      k256[2 * g] = y0; k256[2 * g + 1] = y1;
#else
      unsigned y0, y1, z0, z1;
      if (g < 128) {
        tf2x32(0u, 42u, (unsigned)(2 * g),     (unsigned)(2 * g + 256), y0, y1);
        tf2x32(0u, 42u, (unsigned)(2 * g + 1), (unsigned)(2 * g + 257), z0, z1);
        k256[2 * g] = y0; k256[2 * g + 1] = z0;
      } else {
        tf2x32(0u, 42u, (unsigned)(2 * g - 256), (unsigned)(2 * g),     y0, y1);
        tf2x32(0u, 42u, (unsigned)(2 * g - 255), (unsigned)(2 * g + 1), z0, z1);
        k256[2 * g] = y1; k256[2 * g + 1] = z1;
      }
#endif
    }
    if (g < 2048) ghist[g] = 0u;
    if (g == 112) misc[g] = (int)0xFFFFFFFFu;   // T_spec init: no speculative appends
    else if (g < 256) misc[g] = 0;
  }
  grid.sync();

  // ---- prompt: ONLY layer 15 feeds the output token chain. ----
  if (blk < 16) {
    float* sc = (float*)smA;           // 64 x 129 tile
    int eL = tid & 63, tg = tid >> 6;  // 16 t-groups x 8 tokens
    int e = (blk << 6) + eL;
    const float* wl = Wl15 + e;
    const float* hbase = Ht + tg * 8;
    double acc[8];
#pragma unroll
    for (int k = 0; k < 8; ++k) acc[k] = 0.0;
    for (int d = 0; d < DIM; ++d) {
      float w = wl[(size_t)d * DIM];
      const float* hrow = hbase + d * 128;
#pragma unroll
      for (int k = 0; k < 8; ++k)
        acc[k] = fma((double)hrow[k], (double)w, acc[k]);
    }
#pragma unroll
    for (int k = 0; k < 8; ++k)
      sc[eL * 129 + tg * 8 + k] = (float)acc[k];
    __syncthreads();
    if (tid < 64) {
      float sv = ctx[(blk << 6) + tid];
      for (int t = 0; t < TPROMPT; ++t)
        sv = xla_tanhf(sc[tid * 129 + t] + sv);
      ctx[(blk << 6) + tid] = sv;
    }
    __syncthreads();
  }
  grid.sync();

  // ---- pred_logits (version 0); T_spec = UINT_MAX so no appends ----
  logits_slice(blk, tid, 0, Wo, ctx, temp_p, pen_p, counts, k256,
               skey, marr, ghist, misc, gck, gcv, gcm, hs, s_pd, s_h);
  grid.sync();

  // ---- generation loop:
  //      sampler(blk0) -> token flag -> layer(blk1..16) -> ctx-done flags
  //      -> logits(all) -> grid.sync -> next sampler ----
  for (int i = 0; i < NEVENTS; ++i) {
    if (blk == 0)
      sampler_phase(i, skey, marr, counts, out, ghist, misc, gck, gcv, gcm,
                    s_h, s_val, s_idx, s_ck, s_cv, s_cm, s_misc);
    if (i == NEVENTS - 1) break;       // last model step is dead code
    if (blk >= 1 && blk <= 16)
      layer_slice(blk - 1, tid, i, E, Wl15, ctx, misc, hs, s_rd, s_misc);
    // all blocks: wait for ctx (and, transitively, counts/T_spec/list reset)
    if (tid == 0) {
      const int target = 16 * (i + 1);
      int spins = 0;
      for (;;) {
        int sacc = 0;
#pragma unroll
        for (int j = 0; j < 4; ++j)
          sacc += __hip_atomic_load(misc + 32 + 16 * j, __ATOMIC_RELAXED,
                                    __HIP_MEMORY_SCOPE_AGENT);
        if (sacc >= target) break;
        __builtin_amdgcn_s_sleep(8);
        if (++spins > (1 << 22)) break;
      }
      for (;;) {  // acquire confirm (normally first try)
        int sacc = 0;
#pragma unroll
        for (int j = 0; j < 4; ++j)
          sacc += __hip_atomic_load(misc + 32 + 16 * j, __ATOMIC_ACQUIRE,
                                    __HIP_MEMORY_SCOPE_AGENT);
        if (sacc >= target) break;
        __builtin_amdgcn_s_sleep(16);
      }
    }
    __syncthreads();
    logits_slice(blk, tid, i + 1, Wo, ctx, temp_p, pen_p, counts, k256,
                 skey, marr, ghist, misc, gck, gcv, gcm, hs, s_pd, s_h);
    grid.sync();                       // skey/marr/ghist/list complete before next sampler
  }
}

extern "C" void kernel_launch(void* const* d_in, const int* in_sizes, int n_in,
                              void* d_out, int out_size, void* d_ws, size_t ws_size,
                              hipStream_t stream) {
  const int*   ids  = (const int*)d_in[0];
  const float* E    = (const float*)d_in[1];
  const float* Wl   = (const float*)d_in[2];
  const float* Wo   = (const float*)d_in[3];
  const float* mems = (const float*)d_in[4];
  const int*   tcin = (const int*)d_in[5];
  const float* temp = (const float*)d_in[6];
  const float* pen  = (const float*)d_in[7];
  int* out = (int*)d_out;

  char* ws = (char*)d_ws;
  float*    Ht     = (float*)(ws + 0);        // 1024*128 f32 = 512KB (cand list after prompt)
  float*    ctx    = (float*)(ws + 524288);   // 1024 f32 (layer-15 state)
  unsigned* skey   = (unsigned*)(ws + 589824);// 32000 u32
  float*    marr   = (float*)(ws + 720896);   // 32000 f32
  int*      counts = (int*)(ws + 851968);     // 32000 i32
  unsigned* k256   = (unsigned*)(ws + 979968);// 256*2 u32
  int*      misc   = (int*)(ws + 982016);     // 256 ints (flag lines)
  unsigned* ghist  = (unsigned*)(ws + 983040);// 2048 u32 key histogram
  // total < 1 MB

  void* args[] = { &ids, &E, &Wl, &Wo, &mems, &tcin, &temp, &pen, &out,
                   &Ht, &ctx, &skey, &marr, &counts, &k256, &misc, &ghist };
  hipLaunchCooperativeKernel((const void*)tfxl_kernel, dim3(NBLK), dim3(NTHR),
                             (void**)args, 0, stream);
}